// Round 3
// baseline (1050.072 us; speedup 1.0000x reference)
//
#include <hip/hip_runtime.h>
#include <math.h>

// Problem constants: N=100000, E=400000, G=64, IN=8, H=4, C=64, HD=256.
// GEMMs (Wl/Wr) use split-bf16 MFMA (hi+lo, 3-term) for fp32-class accuracy
// at matrix-core rate. W pre-converted to B-frag layout (hi/lo interleaved).

#define HD 256
#define NHEAD 4
#define CH 64

typedef __attribute__((ext_vector_type(8))) short bf16x8;
typedef __attribute__((ext_vector_type(4))) float f32x4;

__device__ __forceinline__ unsigned f2bf_hibits(float f) {
    unsigned u = __float_as_uint(f);
    return (u + 0x7fffu + ((u >> 16) & 1u)) & 0xffff0000u;   // RNE, as high bits
}

// ---------------------------------------------------------------------------
__global__ void zero_int(int* __restrict__ p, int n) {
    int i = blockIdx.x * 256 + threadIdx.x;
    if (i < n) p[i] = 0;
}

// ---------------------------------------------------------------------------
// CSR build: degree histogram -> 3-step exclusive scan -> scatter
// ---------------------------------------------------------------------------
__global__ void deg_kernel(const int* __restrict__ dst, int* __restrict__ cnt, int E) {
    int e = blockIdx.x * 256 + threadIdx.x;
    if (e < E) atomicAdd(&cnt[dst[e]], 1);
}

__global__ void scan_block(const int* __restrict__ cnt, int* __restrict__ off,
                           int* __restrict__ bsum, int N) {
    __shared__ int s[256];
    int i = blockIdx.x * 256 + threadIdx.x;
    int v = (i < N) ? cnt[i] : 0;
    s[threadIdx.x] = v;
    __syncthreads();
    for (int d = 1; d < 256; d <<= 1) {
        int t = 0;
        if (threadIdx.x >= d) t = s[threadIdx.x - d];
        __syncthreads();
        s[threadIdx.x] += t;
        __syncthreads();
    }
    if (i < N) off[i + 1] = s[threadIdx.x];
    if (threadIdx.x == 255) bsum[blockIdx.x] = s[255];
    if (blockIdx.x == 0 && threadIdx.x == 0) off[0] = 0;
}

__global__ void scan_bsum(const int* __restrict__ bsum, int* __restrict__ bpre, int nb) {
    __shared__ int s[512];
    int t = threadIdx.x;
    s[t] = (t < nb) ? bsum[t] : 0;
    __syncthreads();
    for (int d = 1; d < 512; d <<= 1) {
        int x = 0;
        if (t >= d) x = s[t - d];
        __syncthreads();
        s[t] += x;
        __syncthreads();
    }
    if (t < nb) bpre[t] = s[t] - bsum[t];
}

__global__ void scan_add(int* __restrict__ off, const int* __restrict__ bpre, int N) {
    int i = blockIdx.x * 256 + threadIdx.x;
    if (i < N) off[i + 1] += bpre[blockIdx.x];
}

__global__ void scatter_kernel(const int* __restrict__ dst, const int* __restrict__ off,
                               int* __restrict__ cur, int* __restrict__ eidx, int E) {
    int e = blockIdx.x * 256 + threadIdx.x;
    if (e < E) {
        int d = dst[e];
        int p = atomicAdd(&cur[d], 1);
        eidx[off[d] + p] = e;
    }
}

// ---------------------------------------------------------------------------
// Encoder: h0[N,64] = relu(x[N,8] @ W_enc[8,64] + b_enc)
// ---------------------------------------------------------------------------
__global__ void encoder_kernel(const float* __restrict__ x, const float* __restrict__ W,
                               const float* __restrict__ b, float* __restrict__ h, int N) {
    int idx = blockIdx.x * 256 + threadIdx.x;
    if (idx >= N * 64) return;
    int n = idx >> 6, c = idx & 63;
    float v = b[c];
#pragma unroll
    for (int k = 0; k < 8; ++k) v = fmaf(x[n * 8 + k], W[k * 64 + c], v);
    h[idx] = fmaxf(v, 0.f);
}

// ---------------------------------------------------------------------------
// prep_w: convert Wl,Wr [K,256] fp32 -> B-frag layout, hi/lo bf16 interleaved.
// frag[((ks*32 + ct)*64 + lane)*16]: shorts 0..7 = hi, 8..15 = lo.
// ct<16 -> Wl cols ct*16+..; ct>=16 -> Wr. B-frag: lane holds
// B[k=(lane>>4)*8+j][n=lane&15] within the 32x16 tile.
// ---------------------------------------------------------------------------
__global__ void prep_w(const float* __restrict__ Wl, const float* __restrict__ Wr,
                       ushort* __restrict__ frag, int K) {
    int t = blockIdx.x * 256 + threadIdx.x;
    int total = (K / 32) * 32 * 64;
    if (t >= total) return;
    int l = t & 63;
    int ct = (t >> 6) & 31;
    int ks = t >> 11;
    int n = l & 15, q = l >> 4;
    const float* W = (ct < 16) ? Wl : Wr;
    int col = (ct & 15) * 16 + n;
    ushort* p = frag + (size_t)t * 16;
#pragma unroll
    for (int j = 0; j < 8; ++j) {
        int k = ks * 32 + q * 8 + j;
        float wv = W[(size_t)k * 256 + col];
        unsigned h = f2bf_hibits(wv);
        p[j] = (ushort)(h >> 16);
        float lof = wv - __uint_as_float(h);
        p[8 + j] = (ushort)(f2bf_hibits(lof) >> 16);
    }
}

// ---------------------------------------------------------------------------
// Split-bf16 MFMA dual GEMM: outL/outR[N,256] = A[N,K]@{Wl,Wr} + {bl,br}.
// Block = 256 thr (4 waves), 64 rows/block (wave w -> rows w*16..+15).
// A staged fp32 in LDS (row pad +4 floats => 16B-aligned rows). Per k-step:
// A-frag hi/lo built in registers; inner ct loop (32 tiles = 512 cols) does
// 3 MFMAs per tile, B-frags streamed from L2. No barrier in the K-loop.
// outR may alias A (block reads all its A rows into LDS before any store).
// ---------------------------------------------------------------------------
template <int K>
__global__ __launch_bounds__(256, 2) void gemm_mfma(
    const float* A, const ushort* __restrict__ Bfrag,
    const float* __restrict__ bl, const float* __restrict__ br,
    float* __restrict__ outL, float* outR, int N) {
    constexpr int KS = K / 32;
    constexpr int LDK = K + 4;
    __shared__ float lds[64 * LDK];
    const int t = threadIdx.x;
    const int row0 = blockIdx.x * 64;

    // stage A tile (coalesced float4), zero-fill OOB rows
    {
        const int nf4 = 64 * (K / 4);
        for (int i = t; i < nf4; i += 256) {
            int r = i / (K / 4);
            int k4 = i % (K / 4);
            float4 v = make_float4(0.f, 0.f, 0.f, 0.f);
            if (row0 + r < N) v = *(const float4*)(A + (size_t)(row0 + r) * K + k4 * 4);
            *(float4*)(&lds[r * LDK + k4 * 4]) = v;
        }
    }
    __syncthreads();

    const int w = t >> 6, l = t & 63;
    const int m = l & 15, q = l >> 4;

    f32x4 acc[32];
#pragma unroll
    for (int ct = 0; ct < 32; ++ct) acc[ct] = (f32x4){0.f, 0.f, 0.f, 0.f};

    const float* arow = &lds[(w * 16 + m) * LDK];
    for (int ks = 0; ks < KS; ++ks) {
        float4 a0 = *(const float4*)(arow + ks * 32 + q * 8);
        float4 a1 = *(const float4*)(arow + ks * 32 + q * 8 + 4);
        float av[8] = {a0.x, a0.y, a0.z, a0.w, a1.x, a1.y, a1.z, a1.w};
        bf16x8 ahi, alo;
#pragma unroll
        for (int j = 0; j < 8; ++j) {
            unsigned h = f2bf_hibits(av[j]);
            ahi[j] = (short)(h >> 16);
            float lof = av[j] - __uint_as_float(h);
            alo[j] = (short)(f2bf_hibits(lof) >> 16);
        }
        const ushort* bbase = Bfrag + (((size_t)ks * 32) * 64 + l) * 16;
#pragma unroll
        for (int ct = 0; ct < 32; ++ct) {
            const ushort* p = bbase + (size_t)ct * 64 * 16;
            bf16x8 bhi = *(const bf16x8*)(p);
            bf16x8 blo = *(const bf16x8*)(p + 8);
            acc[ct] = __builtin_amdgcn_mfma_f32_16x16x32_bf16(ahi, bhi, acc[ct], 0, 0, 0);
            acc[ct] = __builtin_amdgcn_mfma_f32_16x16x32_bf16(alo, bhi, acc[ct], 0, 0, 0);
            acc[ct] = __builtin_amdgcn_mfma_f32_16x16x32_bf16(ahi, blo, acc[ct], 0, 0, 0);
        }
    }

    // epilogue: C layout col = lane&15, row = (lane>>4)*4 + reg
#pragma unroll
    for (int ct = 0; ct < 32; ++ct) {
        float bias = (ct < 16) ? bl[ct * 16 + m] : br[(ct - 16) * 16 + m];
        float* outp = (ct < 16) ? outL : outR;
        int colbase = (ct & 15) * 16 + m;
#pragma unroll
        for (int r = 0; r < 4; ++r) {
            int row = row0 + w * 16 + q * 4 + r;
            if (row < N) outp[(size_t)row * 256 + colbase] = acc[ct][r] + bias;
        }
    }
}

// ---------------------------------------------------------------------------
// GATv2 aggregation: one 64-lane wave per destination node, lane = channel.
// Online softmax over incoming edges; single gather pass; no atomics.
// out may ALIAS xr (node i's xr slot read only by node i's wave).
// ---------------------------------------------------------------------------
__global__ __launch_bounds__(256) void gat_aggregate(
    const float* __restrict__ xl, const float* xr,
    const float* __restrict__ eattr, const int* __restrict__ src,
    const int* __restrict__ off, const int* __restrict__ eidx,
    const float* __restrict__ We, const float* __restrict__ att,
    const float* __restrict__ bias, float* out, int N) {
    int node = blockIdx.x * 4 + (threadIdx.x >> 6);
    if (node >= N) return;
    int lane = threadIdx.x & 63;

    float we[NHEAD], at[NHEAD], xrv[NHEAD], m[NHEAD], l[NHEAD], acc[NHEAD];
    size_t nb = (size_t)node * HD;
#pragma unroll
    for (int h = 0; h < NHEAD; ++h) {
        we[h] = We[h * CH + lane];
        at[h] = att[h * CH + lane];
        xrv[h] = xr[nb + h * CH + lane];
        m[h] = -1e30f;
        l[h] = 0.f;
        acc[h] = 0.f;
    }
    int s0 = off[node], s1 = off[node + 1];
    for (int t = s0; t < s1; ++t) {
        int ed = eidx[t];
        int j = src[ed];
        float ea = eattr[ed];
        size_t jb = (size_t)j * HD;
        float xlv[NHEAD], lg[NHEAD];
#pragma unroll
        for (int h = 0; h < NHEAD; ++h) {
            xlv[h] = xl[jb + h * CH + lane];
            float v = fmaf(ea, we[h], xlv[h] + xrv[h]);
            v = (v >= 0.f) ? v : 0.2f * v;   // leaky_relu(0.2)
            lg[h] = at[h] * v;
        }
#pragma unroll
        for (int h = 0; h < NHEAD; ++h) {
            float r = lg[h];
            for (int o = 32; o > 0; o >>= 1) r += __shfl_xor(r, o);
            float mn = fmaxf(m[h], r);
            float sc = expf(m[h] - mn);
            float p = expf(r - mn);
            l[h] = fmaf(l[h], sc, p);
            acc[h] = fmaf(acc[h], sc, p * xlv[h]);
            m[h] = mn;
        }
    }
#pragma unroll
    for (int h = 0; h < NHEAD; ++h) {
        float o = acc[h] / (l[h] + 1e-16f) + bias[h * CH + lane];
        out[nb + h * CH + lane] = fmaxf(o, 0.f);
    }
}

// ---------------------------------------------------------------------------
__device__ __forceinline__ int lowerb(const int* b, int n, int v) {
    int lo = 0, hi = n;
    while (lo < hi) {
        int mid = (lo + hi) >> 1;
        if (b[mid] < v) lo = mid + 1; else hi = mid;
    }
    return lo;
}

__global__ void pool_kernel(const float* __restrict__ h, const int* __restrict__ batch,
                            float* __restrict__ pooled, float* __restrict__ gcnt, int N) {
    int g = blockIdx.x >> 3, part = blockIdx.x & 7;
    int start = lowerb(batch, N, g);
    int end = lowerb(batch, N, g + 1);
    int rows = end - start;
    int r0 = start + (int)((long long)rows * part / 8);
    int r1 = start + (int)((long long)rows * (part + 1) / 8);
    int c = threadIdx.x;
    float s = 0.f;
    for (int r = r0; r < r1; ++r) s += h[(size_t)r * HD + c];
    atomicAdd(&pooled[g * HD + c], s);
    if (part == 0 && c == 0) gcnt[g] = (float)rows;
}

// ---------------------------------------------------------------------------
__global__ void mlp_kernel(const float* __restrict__ pooled, const float* __restrict__ gcnt,
                           const float* __restrict__ W_p1, const float* __restrict__ b_p1,
                           const float* __restrict__ ln_g, const float* __restrict__ ln_b,
                           const float* __restrict__ W_p2, const float* __restrict__ b_p2,
                           const float* __restrict__ W_head, const float* __restrict__ b_head,
                           float* __restrict__ out) {
    int g = blockIdx.x;
    int j = threadIdx.x;
    __shared__ float sh[128];
    __shared__ float red[2];

    float inv = 1.f / fmaxf(gcnt[g], 1.f);
    float v = b_p1[j];
    for (int k = 0; k < 256; ++k) v = fmaf(pooled[g * 256 + k] * inv, W_p1[k * 128 + j], v);

    float s = v;
    for (int o = 32; o > 0; o >>= 1) s += __shfl_xor(s, o);
    if ((j & 63) == 0) red[j >> 6] = s;
    __syncthreads();
    float mu = (red[0] + red[1]) * (1.f / 128.f);
    float d = v - mu;
    float s2 = d * d;
    for (int o = 32; o > 0; o >>= 1) s2 += __shfl_xor(s2, o);
    __syncthreads();
    if ((j & 63) == 0) red[j >> 6] = s2;
    __syncthreads();
    float var = (red[0] + red[1]) * (1.f / 128.f);

    float p = d * rsqrtf(var + 1e-5f) * ln_g[j] + ln_b[j];
    sh[j] = fmaxf(p, 0.f);
    __syncthreads();

    if (j < 64) {
        float q = b_p2[j];
        for (int k = 0; k < 128; ++k) q = fmaf(sh[k], W_p2[k * 64 + j], q);
        q = fmaxf(q, 0.f);
        float t = q * W_head[j];
        for (int o = 32; o > 0; o >>= 1) t += __shfl_xor(t, o);
        if (j == 0) out[g] = t + b_head[0];
    }
}

// ---------------------------------------------------------------------------
extern "C" void kernel_launch(void* const* d_in, const int* in_sizes, int n_in,
                              void* d_out, int out_size, void* d_ws, size_t ws_size,
                              hipStream_t stream) {
    const float* x      = (const float*)d_in[0];
    const float* eattr  = (const float*)d_in[1];
    const int*   src    = (const int*)d_in[2];
    const int*   dst    = (const int*)d_in[3];
    const int*   batch  = (const int*)d_in[4];
    const float* W_enc  = (const float*)d_in[5];
    const float* b_enc  = (const float*)d_in[6];
    const float* g1_Wl  = (const float*)d_in[7];
    const float* g1_bl  = (const float*)d_in[8];
    const float* g1_Wr  = (const float*)d_in[9];
    const float* g1_br  = (const float*)d_in[10];
    const float* g1_We  = (const float*)d_in[11];
    const float* g1_att = (const float*)d_in[12];
    const float* g1_bias= (const float*)d_in[13];
    const float* g2_Wl  = (const float*)d_in[14];
    const float* g2_bl  = (const float*)d_in[15];
    const float* g2_Wr  = (const float*)d_in[16];
    const float* g2_br  = (const float*)d_in[17];
    const float* g2_We  = (const float*)d_in[18];
    const float* g2_att = (const float*)d_in[19];
    const float* g2_bias= (const float*)d_in[20];
    const float* W_p1   = (const float*)d_in[21];
    const float* b_p1   = (const float*)d_in[22];
    const float* ln_g   = (const float*)d_in[23];
    const float* ln_b   = (const float*)d_in[24];
    const float* W_p2   = (const float*)d_in[25];
    const float* b_p2   = (const float*)d_in[26];
    const float* W_head = (const float*)d_in[27];
    const float* b_head = (const float*)d_in[28];

    const int N = in_sizes[0] / 8;   // 100000
    const int E = in_sizes[2];       // 400000

    // workspace layout (~234 MB)
    char* p = (char*)d_ws;
    auto alloc = [&](size_t bytes) -> void* {
        void* r = (void*)p;
        p += (bytes + 255) & ~(size_t)255;
        return r;
    };
    float*  bufA   = (float*)alloc((size_t)N * HD * 4);   // XR / h (in-place chain)
    float*  bufXL  = (float*)alloc((size_t)N * HD * 4);   // XL (gather target)
    float*  bufH0  = (float*)alloc((size_t)N * CH * 4);   // encoder output
    int*    cnt    = (int*)alloc((size_t)N * 4);
    int*    off    = (int*)alloc((size_t)(N + 1) * 4);
    int*    eidx   = (int*)alloc((size_t)E * 4);
    const int nb   = (N + 255) / 256;
    int*    bsum   = (int*)alloc((size_t)nb * 4);
    int*    bpre   = (int*)alloc((size_t)nb * 4);
    float*  pooled = (float*)alloc(64 * HD * 4);
    float*  gcnt   = (float*)alloc(64 * 4);
    ushort* wfrag1 = (ushort*)alloc((size_t)2 * 32 * 64 * 16 * 2);  // 128 KB
    ushort* wfrag2 = (ushort*)alloc((size_t)8 * 32 * 64 * 16 * 2);  // 512 KB

    // ---- weight prep (B-frag hi/lo) ----
    prep_w<<<16, 256, 0, stream>>>(g1_Wl, g1_Wr, wfrag1, 64);
    prep_w<<<64, 256, 0, stream>>>(g2_Wl, g2_Wr, wfrag2, 256);

    // ---- CSR by dst (built once, reused for both GAT layers) ----
    zero_int<<<nb, 256, 0, stream>>>(cnt, N);
    deg_kernel<<<(E + 255) / 256, 256, 0, stream>>>(dst, cnt, E);
    scan_block<<<nb, 256, 0, stream>>>(cnt, off, bsum, N);
    scan_bsum<<<1, 512, 0, stream>>>(bsum, bpre, nb);
    scan_add<<<nb, 256, 0, stream>>>(off, bpre, N);
    zero_int<<<nb, 256, 0, stream>>>(cnt, N);
    scatter_kernel<<<(E + 255) / 256, 256, 0, stream>>>(dst, off, cnt, eidx, E);

    // ---- encoder ----
    encoder_kernel<<<(N * 64 + 255) / 256, 256, 0, stream>>>(x, W_enc, b_enc, bufH0, N);

    const int gblocks = (N + 63) / 64;

    // ---- GAT layer 1: h0 -> XL(bufXL), XR(bufA); aggregate -> h1 in-place(bufA)
    gemm_mfma<64><<<gblocks, 256, 0, stream>>>(
        bufH0, wfrag1, g1_bl, g1_br, bufXL, bufA, N);
    gat_aggregate<<<(N + 3) / 4, 256, 0, stream>>>(
        bufXL, bufA, eattr, src, off, eidx, g1_We, g1_att, g1_bias, bufA, N);

    // ---- GAT layer 2: h1(bufA) -> XL(bufXL), XR in-place(bufA); aggregate -> h2(bufA)
    gemm_mfma<256><<<gblocks, 256, 0, stream>>>(
        bufA, wfrag2, g2_bl, g2_br, bufXL, bufA, N);
    gat_aggregate<<<(N + 3) / 4, 256, 0, stream>>>(
        bufXL, bufA, eattr, src, off, eidx, g2_We, g2_att, g2_bias, bufA, N);

    // ---- pool + MLP head ----
    zero_int<<<(64 * HD + 255) / 256, 256, 0, stream>>>((int*)pooled, 64 * HD);
    pool_kernel<<<64 * 8, 256, 0, stream>>>(bufA, batch, pooled, gcnt, N);
    mlp_kernel<<<64, 128, 0, stream>>>(pooled, gcnt, W_p1, b_p1, ln_g, ln_b,
                                       W_p2, b_p2, W_head, b_head, (float*)d_out);
}

// Round 4
// 864.699 us; speedup vs baseline: 1.2144x; 1.2144x over previous
//
#include <hip/hip_runtime.h>
#include <math.h>

// Problem constants: N=100000, E=400000, G=64, IN=8, H=4, C=64, HD=256.
// GEMMs (Wl/Wr) use split-bf16 MFMA (hi+lo, 3-term) for fp32-class accuracy
// at matrix-core rate. W pre-converted to B-frag layout, hi and lo in
// SEPARATE regions (contiguous 16B/lane loads).
// R3 fix: waves partition COLUMNS (8 ct each), not rows -> B-frag file is
// read once per block instead of once per wave (3.2GB -> 800MB L2 traffic).

#define HD 256
#define NHEAD 4
#define CH 64

typedef __attribute__((ext_vector_type(8))) short bf16x8;
typedef __attribute__((ext_vector_type(4))) float f32x4;

__device__ __forceinline__ unsigned f2bf_hibits(float f) {
    unsigned u = __float_as_uint(f);
    return (u + 0x7fffu + ((u >> 16) & 1u)) & 0xffff0000u;   // RNE, as high bits
}

// ---------------------------------------------------------------------------
__global__ void zero_int(int* __restrict__ p, int n) {
    int i = blockIdx.x * 256 + threadIdx.x;
    if (i < n) p[i] = 0;
}

// ---------------------------------------------------------------------------
// CSR build: degree histogram -> 3-step exclusive scan -> scatter
// ---------------------------------------------------------------------------
__global__ void deg_kernel(const int* __restrict__ dst, int* __restrict__ cnt, int E) {
    int e = blockIdx.x * 256 + threadIdx.x;
    if (e < E) atomicAdd(&cnt[dst[e]], 1);
}

__global__ void scan_block(const int* __restrict__ cnt, int* __restrict__ off,
                           int* __restrict__ bsum, int N) {
    __shared__ int s[256];
    int i = blockIdx.x * 256 + threadIdx.x;
    int v = (i < N) ? cnt[i] : 0;
    s[threadIdx.x] = v;
    __syncthreads();
    for (int d = 1; d < 256; d <<= 1) {
        int t = 0;
        if (threadIdx.x >= d) t = s[threadIdx.x - d];
        __syncthreads();
        s[threadIdx.x] += t;
        __syncthreads();
    }
    if (i < N) off[i + 1] = s[threadIdx.x];
    if (threadIdx.x == 255) bsum[blockIdx.x] = s[255];
    if (blockIdx.x == 0 && threadIdx.x == 0) off[0] = 0;
}

__global__ void scan_bsum(const int* __restrict__ bsum, int* __restrict__ bpre, int nb) {
    __shared__ int s[512];
    int t = threadIdx.x;
    s[t] = (t < nb) ? bsum[t] : 0;
    __syncthreads();
    for (int d = 1; d < 512; d <<= 1) {
        int x = 0;
        if (t >= d) x = s[t - d];
        __syncthreads();
        s[t] += x;
        __syncthreads();
    }
    if (t < nb) bpre[t] = s[t] - bsum[t];
}

__global__ void scan_add(int* __restrict__ off, const int* __restrict__ bpre, int N) {
    int i = blockIdx.x * 256 + threadIdx.x;
    if (i < N) off[i + 1] += bpre[blockIdx.x];
}

__global__ void scatter_kernel(const int* __restrict__ dst, const int* __restrict__ off,
                               int* __restrict__ cur, int* __restrict__ eidx, int E) {
    int e = blockIdx.x * 256 + threadIdx.x;
    if (e < E) {
        int d = dst[e];
        int p = atomicAdd(&cur[d], 1);
        eidx[off[d] + p] = e;
    }
}

// ---------------------------------------------------------------------------
// Encoder: h0[N,64] = relu(x[N,8] @ W_enc[8,64] + b_enc)
// ---------------------------------------------------------------------------
__global__ void encoder_kernel(const float* __restrict__ x, const float* __restrict__ W,
                               const float* __restrict__ b, float* __restrict__ h, int N) {
    int idx = blockIdx.x * 256 + threadIdx.x;
    if (idx >= N * 64) return;
    int n = idx >> 6, c = idx & 63;
    float v = b[c];
#pragma unroll
    for (int k = 0; k < 8; ++k) v = fmaf(x[n * 8 + k], W[k * 64 + c], v);
    h[idx] = fmaxf(v, 0.f);
}

// ---------------------------------------------------------------------------
// prep_w: Wl,Wr [K,256] fp32 -> B-frag layout. hi region then lo region:
// hi[((ks*32+ct)*64 + lane)*8 shorts], lo at +K*64*8 shorts.
// ct<16 -> Wl cols ct*16+n; ct>=16 -> Wr. Lane holds B[k=(l>>4)*8+j][n=l&15].
// ---------------------------------------------------------------------------
__global__ void prep_w(const float* __restrict__ Wl, const float* __restrict__ Wr,
                       ushort* __restrict__ frag, int K) {
    int t = blockIdx.x * 256 + threadIdx.x;
    int total = K * 64;                       // (K/32)*32*64
    if (t >= total) return;
    int l = t & 63;
    int ct = (t >> 6) & 31;
    int ks = t >> 11;
    int n = l & 15, q = l >> 4;
    const float* W = (ct < 16) ? Wl : Wr;
    int col = (ct & 15) * 16 + n;
    ushort* phi = frag + (size_t)t * 8;
    ushort* plo = frag + (size_t)total * 8 + (size_t)t * 8;
#pragma unroll
    for (int j = 0; j < 8; ++j) {
        int k = ks * 32 + q * 8 + j;
        float wv = W[(size_t)k * 256 + col];
        unsigned h = f2bf_hibits(wv);
        phi[j] = (ushort)(h >> 16);
        float lof = wv - __uint_as_float(h);
        plo[j] = (ushort)(f2bf_hibits(lof) >> 16);
    }
}

// ---------------------------------------------------------------------------
// Split-bf16 MFMA dual GEMM: outL/outR[N,256] = A[N,K]@{Wl,Wr} + {bl,br}.
// Block = 256 thr (4 waves), 64 rows. Wave w owns ct = w*8..w*8+7 (128 cols)
// and all 4 row-tiles -> each B frag read once per BLOCK. A staged fp32 in
// LDS; A-frags rebuilt per ks (redundant across waves, VALU hidden by MFMA).
// outR may alias A (block reads its A rows before any store).
// ---------------------------------------------------------------------------
template <int K>
__global__ __launch_bounds__(256, 2) void gemm_mfma(
    const float* A, const ushort* __restrict__ Bfrag,
    const float* __restrict__ bl, const float* __restrict__ br,
    float* __restrict__ outL, float* outR, int N) {
    constexpr int KS = K / 32;
    constexpr int LDK = K + 4;
    constexpr size_t LO_OFF = (size_t)K * 64 * 8;   // shorts
    __shared__ float lds[64 * LDK];
    const int t = threadIdx.x;
    const int row0 = blockIdx.x * 64;

    // stage A tile (coalesced float4), zero-fill OOB rows
    {
        const int nf4 = 64 * (K / 4);
        for (int i = t; i < nf4; i += 256) {
            int r = i / (K / 4);
            int k4 = i % (K / 4);
            float4 v = make_float4(0.f, 0.f, 0.f, 0.f);
            if (row0 + r < N) v = *(const float4*)(A + (size_t)(row0 + r) * K + k4 * 4);
            *(float4*)(&lds[r * LDK + k4 * 4]) = v;
        }
    }
    __syncthreads();

    const int w = t >> 6, l = t & 63;
    const int m = l & 15, q = l >> 4;

    f32x4 acc[4][8];
#pragma unroll
    for (int rt = 0; rt < 4; ++rt)
#pragma unroll
        for (int c = 0; c < 8; ++c) acc[rt][c] = (f32x4){0.f, 0.f, 0.f, 0.f};

    for (int ks = 0; ks < KS; ++ks) {
        // build A-frags for all 4 row-tiles (hi/lo)
        bf16x8 ahi[4], alo[4];
#pragma unroll
        for (int rt = 0; rt < 4; ++rt) {
            const float* arow = &lds[(rt * 16 + m) * LDK + ks * 32 + q * 8];
            float4 a0 = *(const float4*)(arow);
            float4 a1 = *(const float4*)(arow + 4);
            float av[8] = {a0.x, a0.y, a0.z, a0.w, a1.x, a1.y, a1.z, a1.w};
#pragma unroll
            for (int j = 0; j < 8; ++j) {
                unsigned h = f2bf_hibits(av[j]);
                ahi[rt][j] = (short)(h >> 16);
                float lof = av[j] - __uint_as_float(h);
                alo[rt][j] = (short)(f2bf_hibits(lof) >> 16);
            }
        }
        // stream this wave's 8 B-frag pairs; 3-term split MFMA
#pragma unroll
        for (int c = 0; c < 8; ++c) {
            size_t e = ((size_t)(ks * 32 + w * 8 + c) * 64 + l) * 8;
            bf16x8 bhi = *(const bf16x8*)(Bfrag + e);
            bf16x8 blo = *(const bf16x8*)(Bfrag + LO_OFF + e);
#pragma unroll
            for (int rt = 0; rt < 4; ++rt) {
                acc[rt][c] = __builtin_amdgcn_mfma_f32_16x16x32_bf16(ahi[rt], bhi, acc[rt][c], 0, 0, 0);
                acc[rt][c] = __builtin_amdgcn_mfma_f32_16x16x32_bf16(alo[rt], bhi, acc[rt][c], 0, 0, 0);
                acc[rt][c] = __builtin_amdgcn_mfma_f32_16x16x32_bf16(ahi[rt], blo, acc[rt][c], 0, 0, 0);
            }
        }
    }

    // epilogue: C layout col = lane&15 (n), row = (lane>>4)*4 + reg
    const int ct0 = w * 8;
    const float* bias = (ct0 < 16) ? bl : br;
    float* outp = (ct0 < 16) ? outL : outR;
#pragma unroll
    for (int c = 0; c < 8; ++c) {
        int ct = ct0 + c;
        int colbase = (ct & 15) * 16 + m;
        float bb = bias[colbase];
#pragma unroll
        for (int rt = 0; rt < 4; ++rt) {
#pragma unroll
            for (int r = 0; r < 4; ++r) {
                int row = row0 + rt * 16 + q * 4 + r;
                if (row < N) outp[(size_t)row * 256 + colbase] = acc[rt][c][r] + bb;
            }
        }
    }
}

// ---------------------------------------------------------------------------
// GATv2 aggregation: one 64-lane wave per destination node, lane = channel.
// Online softmax over incoming edges; single gather pass; no atomics.
// out may ALIAS xr (node i's xr slot read only by node i's wave).
// ---------------------------------------------------------------------------
__global__ __launch_bounds__(256) void gat_aggregate(
    const float* __restrict__ xl, const float* xr,
    const float* __restrict__ eattr, const int* __restrict__ src,
    const int* __restrict__ off, const int* __restrict__ eidx,
    const float* __restrict__ We, const float* __restrict__ att,
    const float* __restrict__ bias, float* out, int N) {
    int node = blockIdx.x * 4 + (threadIdx.x >> 6);
    if (node >= N) return;
    int lane = threadIdx.x & 63;

    float we[NHEAD], at[NHEAD], xrv[NHEAD], m[NHEAD], l[NHEAD], acc[NHEAD];
    size_t nb = (size_t)node * HD;
#pragma unroll
    for (int h = 0; h < NHEAD; ++h) {
        we[h] = We[h * CH + lane];
        at[h] = att[h * CH + lane];
        xrv[h] = xr[nb + h * CH + lane];
        m[h] = -1e30f;
        l[h] = 0.f;
        acc[h] = 0.f;
    }
    int s0 = off[node], s1 = off[node + 1];
    for (int t = s0; t < s1; ++t) {
        int ed = eidx[t];
        int j = src[ed];
        float ea = eattr[ed];
        size_t jb = (size_t)j * HD;
        float xlv[NHEAD], lg[NHEAD];
#pragma unroll
        for (int h = 0; h < NHEAD; ++h) {
            xlv[h] = xl[jb + h * CH + lane];
            float v = fmaf(ea, we[h], xlv[h] + xrv[h]);
            v = (v >= 0.f) ? v : 0.2f * v;   // leaky_relu(0.2)
            lg[h] = at[h] * v;
        }
#pragma unroll
        for (int h = 0; h < NHEAD; ++h) {
            float r = lg[h];
            for (int o = 32; o > 0; o >>= 1) r += __shfl_xor(r, o);
            float mn = fmaxf(m[h], r);
            float sc = expf(m[h] - mn);
            float p = expf(r - mn);
            l[h] = fmaf(l[h], sc, p);
            acc[h] = fmaf(acc[h], sc, p * xlv[h]);
            m[h] = mn;
        }
    }
#pragma unroll
    for (int h = 0; h < NHEAD; ++h) {
        float o = acc[h] / (l[h] + 1e-16f) + bias[h * CH + lane];
        out[nb + h * CH + lane] = fmaxf(o, 0.f);
    }
}

// ---------------------------------------------------------------------------
__device__ __forceinline__ int lowerb(const int* b, int n, int v) {
    int lo = 0, hi = n;
    while (lo < hi) {
        int mid = (lo + hi) >> 1;
        if (b[mid] < v) lo = mid + 1; else hi = mid;
    }
    return lo;
}

__global__ void pool_kernel(const float* __restrict__ h, const int* __restrict__ batch,
                            float* __restrict__ pooled, float* __restrict__ gcnt, int N) {
    int g = blockIdx.x >> 3, part = blockIdx.x & 7;
    int start = lowerb(batch, N, g);
    int end = lowerb(batch, N, g + 1);
    int rows = end - start;
    int r0 = start + (int)((long long)rows * part / 8);
    int r1 = start + (int)((long long)rows * (part + 1) / 8);
    int c = threadIdx.x;
    float s = 0.f;
    for (int r = r0; r < r1; ++r) s += h[(size_t)r * HD + c];
    atomicAdd(&pooled[g * HD + c], s);
    if (part == 0 && c == 0) gcnt[g] = (float)rows;
}

// ---------------------------------------------------------------------------
__global__ void mlp_kernel(const float* __restrict__ pooled, const float* __restrict__ gcnt,
                           const float* __restrict__ W_p1, const float* __restrict__ b_p1,
                           const float* __restrict__ ln_g, const float* __restrict__ ln_b,
                           const float* __restrict__ W_p2, const float* __restrict__ b_p2,
                           const float* __restrict__ W_head, const float* __restrict__ b_head,
                           float* __restrict__ out) {
    int g = blockIdx.x;
    int j = threadIdx.x;
    __shared__ float sh[128];
    __shared__ float red[2];

    float inv = 1.f / fmaxf(gcnt[g], 1.f);
    float v = b_p1[j];
    for (int k = 0; k < 256; ++k) v = fmaf(pooled[g * 256 + k] * inv, W_p1[k * 128 + j], v);

    float s = v;
    for (int o = 32; o > 0; o >>= 1) s += __shfl_xor(s, o);
    if ((j & 63) == 0) red[j >> 6] = s;
    __syncthreads();
    float mu = (red[0] + red[1]) * (1.f / 128.f);
    float d = v - mu;
    float s2 = d * d;
    for (int o = 32; o > 0; o >>= 1) s2 += __shfl_xor(s2, o);
    __syncthreads();
    if ((j & 63) == 0) red[j >> 6] = s2;
    __syncthreads();
    float var = (red[0] + red[1]) * (1.f / 128.f);

    float p = d * rsqrtf(var + 1e-5f) * ln_g[j] + ln_b[j];
    sh[j] = fmaxf(p, 0.f);
    __syncthreads();

    if (j < 64) {
        float q = b_p2[j];
        for (int k = 0; k < 128; ++k) q = fmaf(sh[k], W_p2[k * 64 + j], q);
        q = fmaxf(q, 0.f);
        float t = q * W_head[j];
        for (int o = 32; o > 0; o >>= 1) t += __shfl_xor(t, o);
        if (j == 0) out[g] = t + b_head[0];
    }
}

// ---------------------------------------------------------------------------
extern "C" void kernel_launch(void* const* d_in, const int* in_sizes, int n_in,
                              void* d_out, int out_size, void* d_ws, size_t ws_size,
                              hipStream_t stream) {
    const float* x      = (const float*)d_in[0];
    const float* eattr  = (const float*)d_in[1];
    const int*   src    = (const int*)d_in[2];
    const int*   dst    = (const int*)d_in[3];
    const int*   batch  = (const int*)d_in[4];
    const float* W_enc  = (const float*)d_in[5];
    const float* b_enc  = (const float*)d_in[6];
    const float* g1_Wl  = (const float*)d_in[7];
    const float* g1_bl  = (const float*)d_in[8];
    const float* g1_Wr  = (const float*)d_in[9];
    const float* g1_br  = (const float*)d_in[10];
    const float* g1_We  = (const float*)d_in[11];
    const float* g1_att = (const float*)d_in[12];
    const float* g1_bias= (const float*)d_in[13];
    const float* g2_Wl  = (const float*)d_in[14];
    const float* g2_bl  = (const float*)d_in[15];
    const float* g2_Wr  = (const float*)d_in[16];
    const float* g2_br  = (const float*)d_in[17];
    const float* g2_We  = (const float*)d_in[18];
    const float* g2_att = (const float*)d_in[19];
    const float* g2_bias= (const float*)d_in[20];
    const float* W_p1   = (const float*)d_in[21];
    const float* b_p1   = (const float*)d_in[22];
    const float* ln_g   = (const float*)d_in[23];
    const float* ln_b   = (const float*)d_in[24];
    const float* W_p2   = (const float*)d_in[25];
    const float* b_p2   = (const float*)d_in[26];
    const float* W_head = (const float*)d_in[27];
    const float* b_head = (const float*)d_in[28];

    const int N = in_sizes[0] / 8;   // 100000
    const int E = in_sizes[2];       // 400000

    // workspace layout (~234 MB)
    char* p = (char*)d_ws;
    auto alloc = [&](size_t bytes) -> void* {
        void* r = (void*)p;
        p += (bytes + 255) & ~(size_t)255;
        return r;
    };
    float*  bufA   = (float*)alloc((size_t)N * HD * 4);   // XR / h (in-place chain)
    float*  bufXL  = (float*)alloc((size_t)N * HD * 4);   // XL (gather target)
    float*  bufH0  = (float*)alloc((size_t)N * CH * 4);   // encoder output
    int*    cnt    = (int*)alloc((size_t)N * 4);
    int*    off    = (int*)alloc((size_t)(N + 1) * 4);
    int*    eidx   = (int*)alloc((size_t)E * 4);
    const int nb   = (N + 255) / 256;
    int*    bsum   = (int*)alloc((size_t)nb * 4);
    int*    bpre   = (int*)alloc((size_t)nb * 4);
    float*  pooled = (float*)alloc(64 * HD * 4);
    float*  gcnt   = (float*)alloc(64 * 4);
    ushort* wfrag1 = (ushort*)alloc((size_t)64 * 64 * 16 * 2 * 2);   // 128 KB (K=64)
    ushort* wfrag2 = (ushort*)alloc((size_t)256 * 64 * 16 * 2 * 2);  // 512 KB (K=256)

    // ---- weight prep (B-frag, hi/lo regions) ----
    prep_w<<<16, 256, 0, stream>>>(g1_Wl, g1_Wr, wfrag1, 64);
    prep_w<<<64, 256, 0, stream>>>(g2_Wl, g2_Wr, wfrag2, 256);

    // ---- CSR by dst (built once, reused for both GAT layers) ----
    zero_int<<<nb, 256, 0, stream>>>(cnt, N);
    deg_kernel<<<(E + 255) / 256, 256, 0, stream>>>(dst, cnt, E);
    scan_block<<<nb, 256, 0, stream>>>(cnt, off, bsum, N);
    scan_bsum<<<1, 512, 0, stream>>>(bsum, bpre, nb);
    scan_add<<<nb, 256, 0, stream>>>(off, bpre, N);
    zero_int<<<nb, 256, 0, stream>>>(cnt, N);
    scatter_kernel<<<(E + 255) / 256, 256, 0, stream>>>(dst, off, cnt, eidx, E);

    // ---- encoder ----
    encoder_kernel<<<(N * 64 + 255) / 256, 256, 0, stream>>>(x, W_enc, b_enc, bufH0, N);

    const int gblocks = (N + 63) / 64;

    // ---- GAT layer 1: h0 -> XL(bufXL), XR(bufA); aggregate -> h1 in-place(bufA)
    gemm_mfma<64><<<gblocks, 256, 0, stream>>>(
        bufH0, wfrag1, g1_bl, g1_br, bufXL, bufA, N);
    gat_aggregate<<<(N + 3) / 4, 256, 0, stream>>>(
        bufXL, bufA, eattr, src, off, eidx, g1_We, g1_att, g1_bias, bufA, N);

    // ---- GAT layer 2: h1(bufA) -> XL(bufXL), XR in-place(bufA); aggregate -> h2(bufA)
    gemm_mfma<256><<<gblocks, 256, 0, stream>>>(
        bufA, wfrag2, g2_bl, g2_br, bufXL, bufA, N);
    gat_aggregate<<<(N + 3) / 4, 256, 0, stream>>>(
        bufXL, bufA, eattr, src, off, eidx, g2_We, g2_att, g2_bias, bufA, N);

    // ---- pool + MLP head ----
    zero_int<<<(64 * HD + 255) / 256, 256, 0, stream>>>((int*)pooled, 64 * HD);
    pool_kernel<<<64 * 8, 256, 0, stream>>>(bufA, batch, pooled, gcnt, N);
    mlp_kernel<<<64, 128, 0, stream>>>(pooled, gcnt, W_p1, b_p1, ln_g, ln_b,
                                       W_p2, b_p2, W_head, b_head, (float*)d_out);
}

// Round 5
// 713.235 us; speedup vs baseline: 1.4723x; 1.2124x over previous
//
#include <hip/hip_runtime.h>
#include <math.h>

// Problem constants: N=100000, E=400000, G=64, IN=8, H=4, C=64, HD=256.
// GEMMs use split-bf16 MFMA (hi+lo, 3-term) for fp32-class accuracy.
// R5: A pre-converted to hi/lo bf16 MFMA A-frags at LDS staging (64KB exactly,
// conflict-free b128 reads, no in-loop VALU convert); 512-thr blocks with
// wave = 4ct x 4rt (acc 64 AGPR) + launch_bounds(512,4) -> 16 waves/CU.

#define HD 256
#define NHEAD 4
#define CH 64

typedef __attribute__((ext_vector_type(8))) short bf16x8;
typedef __attribute__((ext_vector_type(4))) float f32x4;

__device__ __forceinline__ unsigned f2bf_hibits(float f) {
    unsigned u = __float_as_uint(f);
    return (u + 0x7fffu + ((u >> 16) & 1u)) & 0xffff0000u;   // RNE, as high bits
}

// ---------------------------------------------------------------------------
__global__ void zero_int(int* __restrict__ p, int n) {
    int i = blockIdx.x * 256 + threadIdx.x;
    if (i < n) p[i] = 0;
}

// ---------------------------------------------------------------------------
// CSR build: degree histogram -> 3-step exclusive scan -> scatter
// ---------------------------------------------------------------------------
__global__ void deg_kernel(const int* __restrict__ dst, int* __restrict__ cnt, int E) {
    int e = blockIdx.x * 256 + threadIdx.x;
    if (e < E) atomicAdd(&cnt[dst[e]], 1);
}

__global__ void scan_block(const int* __restrict__ cnt, int* __restrict__ off,
                           int* __restrict__ bsum, int N) {
    __shared__ int s[256];
    int i = blockIdx.x * 256 + threadIdx.x;
    int v = (i < N) ? cnt[i] : 0;
    s[threadIdx.x] = v;
    __syncthreads();
    for (int d = 1; d < 256; d <<= 1) {
        int t = 0;
        if (threadIdx.x >= d) t = s[threadIdx.x - d];
        __syncthreads();
        s[threadIdx.x] += t;
        __syncthreads();
    }
    if (i < N) off[i + 1] = s[threadIdx.x];
    if (threadIdx.x == 255) bsum[blockIdx.x] = s[255];
    if (blockIdx.x == 0 && threadIdx.x == 0) off[0] = 0;
}

__global__ void scan_bsum(const int* __restrict__ bsum, int* __restrict__ bpre, int nb) {
    __shared__ int s[512];
    int t = threadIdx.x;
    s[t] = (t < nb) ? bsum[t] : 0;
    __syncthreads();
    for (int d = 1; d < 512; d <<= 1) {
        int x = 0;
        if (t >= d) x = s[t - d];
        __syncthreads();
        s[t] += x;
        __syncthreads();
    }
    if (t < nb) bpre[t] = s[t] - bsum[t];
}

__global__ void scan_add(int* __restrict__ off, const int* __restrict__ bpre, int N) {
    int i = blockIdx.x * 256 + threadIdx.x;
    if (i < N) off[i + 1] += bpre[blockIdx.x];
}

__global__ void scatter_kernel(const int* __restrict__ dst, const int* __restrict__ off,
                               int* __restrict__ cur, int* __restrict__ eidx, int E) {
    int e = blockIdx.x * 256 + threadIdx.x;
    if (e < E) {
        int d = dst[e];
        int p = atomicAdd(&cur[d], 1);
        eidx[off[d] + p] = e;
    }
}

// ---------------------------------------------------------------------------
// Encoder: h0[N,64] = relu(x[N,8] @ W_enc[8,64] + b_enc)
// ---------------------------------------------------------------------------
__global__ void encoder_kernel(const float* __restrict__ x, const float* __restrict__ W,
                               const float* __restrict__ b, float* __restrict__ h, int N) {
    int idx = blockIdx.x * 256 + threadIdx.x;
    if (idx >= N * 64) return;
    int n = idx >> 6, c = idx & 63;
    float v = b[c];
#pragma unroll
    for (int k = 0; k < 8; ++k) v = fmaf(x[n * 8 + k], W[k * 64 + c], v);
    h[idx] = fmaxf(v, 0.f);
}

// ---------------------------------------------------------------------------
// prep_w: Wl,Wr [K,256] fp32 -> B-frag layout. hi region then lo region:
// hi[((ks*32+ct)*64 + lane)*8 shorts], lo at +K*64*8 shorts.
// ct<16 -> Wl cols ct*16+n; ct>=16 -> Wr. Lane holds B[k=(l>>4)*8+j][n=l&15].
// ---------------------------------------------------------------------------
__global__ void prep_w(const float* __restrict__ Wl, const float* __restrict__ Wr,
                       ushort* __restrict__ frag, int K) {
    int t = blockIdx.x * 256 + threadIdx.x;
    int total = K * 64;
    if (t >= total) return;
    int l = t & 63;
    int ct = (t >> 6) & 31;
    int ks = t >> 11;
    int n = l & 15, q = l >> 4;
    const float* W = (ct < 16) ? Wl : Wr;
    int col = (ct & 15) * 16 + n;
    ushort* phi = frag + (size_t)t * 8;
    ushort* plo = frag + (size_t)total * 8 + (size_t)t * 8;
#pragma unroll
    for (int j = 0; j < 8; ++j) {
        int k = ks * 32 + q * 8 + j;
        float wv = W[(size_t)k * 256 + col];
        unsigned h = f2bf_hibits(wv);
        phi[j] = (ushort)(h >> 16);
        float lof = wv - __uint_as_float(h);
        plo[j] = (ushort)(f2bf_hibits(lof) >> 16);
    }
}

// ---------------------------------------------------------------------------
// Split-bf16 MFMA dual GEMM: outL/outR[N,256] = A[N,K]@{Wl,Wr} + {bl,br}.
// Block = 512 thr (8 waves), 64 rows. Staging converts A to hi/lo bf16
// A-frags in LDS (frag cell = ((ks*4+rt)*64 + lane), 16B/cell) -> K-loop
// does only ds_read_b128 + global B loads + MFMA. Wave w: ct = w*4..+3,
// rt = 0..3. outR may alias A (A fully consumed at staging).
// ---------------------------------------------------------------------------
template <int K>
__global__ __launch_bounds__(512, 4) void gemm_mfma(
    const float* A, const ushort* __restrict__ Bfrag,
    const float* __restrict__ bl, const float* __restrict__ br,
    float* __restrict__ outL, float* outR, int N) {
    constexpr int KS = K / 32;
    constexpr int C4 = K / 4;                    // float4s per A row
    constexpr int LC4 = (K == 256) ? 6 : 4;      // log2(C4)
    constexpr int FRAG_SHORTS = KS * 4 * 64 * 8; // per region
    constexpr size_t LO_OFF = (size_t)K * 64 * 8;
    __shared__ ushort fragHi[FRAG_SHORTS];
    __shared__ ushort fragLo[FRAG_SHORTS];

    const int t = threadIdx.x;
    const int row0 = blockIdx.x * 64;

    // ---- stage A -> hi/lo A-frags in LDS.
    // job jj: m = jj&15 (row within rt-group), c4 = (jj>>4)&(C4-1), rg = rest.
    // Wave reads 16 rows x 64B (coalesced per-row segments); LDS writes spread
    // across banks via m.
#pragma unroll
    for (int it = 0; it < (64 * C4) / 512; ++it) {
        int jj = it * 512 + t;
        int m = jj & 15;
        int c4 = (jj >> 4) & (C4 - 1);
        int rg = jj >> (4 + LC4);
        int row = row0 + rg * 16 + m;
        float4 v = make_float4(0.f, 0.f, 0.f, 0.f);
        if (row < N) v = *(const float4*)(A + (size_t)row * K + c4 * 4);
        int c = c4 * 4;
        int ks = c >> 5, q = (c >> 3) & 3, j = c & 7;
        int cell = (ks * 4 + rg) * 64 + m + 16 * q;
        float f[4] = {v.x, v.y, v.z, v.w};
        ushort h4[4], l4[4];
#pragma unroll
        for (int u = 0; u < 4; ++u) {
            unsigned hb = f2bf_hibits(f[u]);
            h4[u] = (ushort)(hb >> 16);
            l4[u] = (ushort)(f2bf_hibits(f[u] - __uint_as_float(hb)) >> 16);
        }
        *(ushort4*)(fragHi + cell * 8 + j) = make_ushort4(h4[0], h4[1], h4[2], h4[3]);
        *(ushort4*)(fragLo + cell * 8 + j) = make_ushort4(l4[0], l4[1], l4[2], l4[3]);
    }
    __syncthreads();

    const int w = t >> 6, l = t & 63;
    const int ct0 = w * 4;

    f32x4 acc[4][4];
#pragma unroll
    for (int rt = 0; rt < 4; ++rt)
#pragma unroll
        for (int c = 0; c < 4; ++c) acc[rt][c] = (f32x4){0.f, 0.f, 0.f, 0.f};

    for (int ks = 0; ks < KS; ++ks) {
        bf16x8 ah[4], al[4];
#pragma unroll
        for (int rt = 0; rt < 4; ++rt) {
            int cell = (ks * 4 + rt) * 64 + l;
            ah[rt] = *(const bf16x8*)(fragHi + cell * 8);
            al[rt] = *(const bf16x8*)(fragLo + cell * 8);
        }
#pragma unroll
        for (int c = 0; c < 4; ++c) {
            size_t e = ((size_t)(ks * 32 + ct0 + c) * 64 + l) * 8;
            bf16x8 bh = *(const bf16x8*)(Bfrag + e);
            bf16x8 bo = *(const bf16x8*)(Bfrag + LO_OFF + e);
#pragma unroll
            for (int rt = 0; rt < 4; ++rt) {
                acc[rt][c] = __builtin_amdgcn_mfma_f32_16x16x32_bf16(ah[rt], bh, acc[rt][c], 0, 0, 0);
                acc[rt][c] = __builtin_amdgcn_mfma_f32_16x16x32_bf16(al[rt], bh, acc[rt][c], 0, 0, 0);
                acc[rt][c] = __builtin_amdgcn_mfma_f32_16x16x32_bf16(ah[rt], bo, acc[rt][c], 0, 0, 0);
            }
        }
    }

    // epilogue: C layout col = lane&15 (n), row = (lane>>4)*4 + reg
    const int m = l & 15, q = l >> 4;
    const float* bias = (w < 4) ? bl : br;
    float* outp = (w < 4) ? outL : outR;
#pragma unroll
    for (int c = 0; c < 4; ++c) {
        int colbase = ((ct0 + c) & 15) * 16 + m;
        float bb = bias[colbase];
#pragma unroll
        for (int rt = 0; rt < 4; ++rt) {
#pragma unroll
            for (int r = 0; r < 4; ++r) {
                int row = row0 + rt * 16 + q * 4 + r;
                if (row < N) outp[(size_t)row * 256 + colbase] = acc[rt][c][r] + bb;
            }
        }
    }
}

// ---------------------------------------------------------------------------
// GATv2 aggregation: one 64-lane wave per destination node, lane = channel.
// Online softmax over incoming edges; single gather pass; no atomics.
// out may ALIAS xr (node i's xr slot read only by node i's wave).
// ---------------------------------------------------------------------------
__global__ __launch_bounds__(256) void gat_aggregate(
    const float* __restrict__ xl, const float* xr,
    const float* __restrict__ eattr, const int* __restrict__ src,
    const int* __restrict__ off, const int* __restrict__ eidx,
    const float* __restrict__ We, const float* __restrict__ att,
    const float* __restrict__ bias, float* out, int N) {
    int node = blockIdx.x * 4 + (threadIdx.x >> 6);
    if (node >= N) return;
    int lane = threadIdx.x & 63;

    float we[NHEAD], at[NHEAD], xrv[NHEAD], m[NHEAD], l[NHEAD], acc[NHEAD];
    size_t nb = (size_t)node * HD;
#pragma unroll
    for (int h = 0; h < NHEAD; ++h) {
        we[h] = We[h * CH + lane];
        at[h] = att[h * CH + lane];
        xrv[h] = xr[nb + h * CH + lane];
        m[h] = -1e30f;
        l[h] = 0.f;
        acc[h] = 0.f;
    }
    int s0 = off[node], s1 = off[node + 1];
    for (int t = s0; t < s1; ++t) {
        int ed = eidx[t];
        int j = src[ed];
        float ea = eattr[ed];
        size_t jb = (size_t)j * HD;
        float xlv[NHEAD], lg[NHEAD];
#pragma unroll
        for (int h = 0; h < NHEAD; ++h) {
            xlv[h] = xl[jb + h * CH + lane];
            float v = fmaf(ea, we[h], xlv[h] + xrv[h]);
            v = (v >= 0.f) ? v : 0.2f * v;   // leaky_relu(0.2)
            lg[h] = at[h] * v;
        }
#pragma unroll
        for (int h = 0; h < NHEAD; ++h) {
            float r = lg[h];
            for (int o = 32; o > 0; o >>= 1) r += __shfl_xor(r, o);
            float mn = fmaxf(m[h], r);
            float sc = expf(m[h] - mn);
            float p = expf(r - mn);
            l[h] = fmaf(l[h], sc, p);
            acc[h] = fmaf(acc[h], sc, p * xlv[h]);
            m[h] = mn;
        }
    }
#pragma unroll
    for (int h = 0; h < NHEAD; ++h) {
        float o = acc[h] / (l[h] + 1e-16f) + bias[h * CH + lane];
        out[nb + h * CH + lane] = fmaxf(o, 0.f);
    }
}

// ---------------------------------------------------------------------------
__device__ __forceinline__ int lowerb(const int* b, int n, int v) {
    int lo = 0, hi = n;
    while (lo < hi) {
        int mid = (lo + hi) >> 1;
        if (b[mid] < v) lo = mid + 1; else hi = mid;
    }
    return lo;
}

__global__ void pool_kernel(const float* __restrict__ h, const int* __restrict__ batch,
                            float* __restrict__ pooled, float* __restrict__ gcnt, int N) {
    int g = blockIdx.x >> 3, part = blockIdx.x & 7;
    int start = lowerb(batch, N, g);
    int end = lowerb(batch, N, g + 1);
    int rows = end - start;
    int r0 = start + (int)((long long)rows * part / 8);
    int r1 = start + (int)((long long)rows * (part + 1) / 8);
    int c = threadIdx.x;
    float s = 0.f;
    for (int r = r0; r < r1; ++r) s += h[(size_t)r * HD + c];
    atomicAdd(&pooled[g * HD + c], s);
    if (part == 0 && c == 0) gcnt[g] = (float)rows;
}

// ---------------------------------------------------------------------------
__global__ void mlp_kernel(const float* __restrict__ pooled, const float* __restrict__ gcnt,
                           const float* __restrict__ W_p1, const float* __restrict__ b_p1,
                           const float* __restrict__ ln_g, const float* __restrict__ ln_b,
                           const float* __restrict__ W_p2, const float* __restrict__ b_p2,
                           const float* __restrict__ W_head, const float* __restrict__ b_head,
                           float* __restrict__ out) {
    int g = blockIdx.x;
    int j = threadIdx.x;
    __shared__ float sh[128];
    __shared__ float red[2];

    float inv = 1.f / fmaxf(gcnt[g], 1.f);
    float v = b_p1[j];
    for (int k = 0; k < 256; ++k) v = fmaf(pooled[g * 256 + k] * inv, W_p1[k * 128 + j], v);

    float s = v;
    for (int o = 32; o > 0; o >>= 1) s += __shfl_xor(s, o);
    if ((j & 63) == 0) red[j >> 6] = s;
    __syncthreads();
    float mu = (red[0] + red[1]) * (1.f / 128.f);
    float d = v - mu;
    float s2 = d * d;
    for (int o = 32; o > 0; o >>= 1) s2 += __shfl_xor(s2, o);
    __syncthreads();
    if ((j & 63) == 0) red[j >> 6] = s2;
    __syncthreads();
    float var = (red[0] + red[1]) * (1.f / 128.f);

    float p = d * rsqrtf(var + 1e-5f) * ln_g[j] + ln_b[j];
    sh[j] = fmaxf(p, 0.f);
    __syncthreads();

    if (j < 64) {
        float q = b_p2[j];
        for (int k = 0; k < 128; ++k) q = fmaf(sh[k], W_p2[k * 64 + j], q);
        q = fmaxf(q, 0.f);
        float t = q * W_head[j];
        for (int o = 32; o > 0; o >>= 1) t += __shfl_xor(t, o);
        if (j == 0) out[g] = t + b_head[0];
    }
}

// ---------------------------------------------------------------------------
extern "C" void kernel_launch(void* const* d_in, const int* in_sizes, int n_in,
                              void* d_out, int out_size, void* d_ws, size_t ws_size,
                              hipStream_t stream) {
    const float* x      = (const float*)d_in[0];
    const float* eattr  = (const float*)d_in[1];
    const int*   src    = (const int*)d_in[2];
    const int*   dst    = (const int*)d_in[3];
    const int*   batch  = (const int*)d_in[4];
    const float* W_enc  = (const float*)d_in[5];
    const float* b_enc  = (const float*)d_in[6];
    const float* g1_Wl  = (const float*)d_in[7];
    const float* g1_bl  = (const float*)d_in[8];
    const float* g1_Wr  = (const float*)d_in[9];
    const float* g1_br  = (const float*)d_in[10];
    const float* g1_We  = (const float*)d_in[11];
    const float* g1_att = (const float*)d_in[12];
    const float* g1_bias= (const float*)d_in[13];
    const float* g2_Wl  = (const float*)d_in[14];
    const float* g2_bl  = (const float*)d_in[15];
    const float* g2_Wr  = (const float*)d_in[16];
    const float* g2_br  = (const float*)d_in[17];
    const float* g2_We  = (const float*)d_in[18];
    const float* g2_att = (const float*)d_in[19];
    const float* g2_bias= (const float*)d_in[20];
    const float* W_p1   = (const float*)d_in[21];
    const float* b_p1   = (const float*)d_in[22];
    const float* ln_g   = (const float*)d_in[23];
    const float* ln_b   = (const float*)d_in[24];
    const float* W_p2   = (const float*)d_in[25];
    const float* b_p2   = (const float*)d_in[26];
    const float* W_head = (const float*)d_in[27];
    const float* b_head = (const float*)d_in[28];

    const int N = in_sizes[0] / 8;   // 100000
    const int E = in_sizes[2];       // 400000

    // workspace layout (~234 MB)
    char* p = (char*)d_ws;
    auto alloc = [&](size_t bytes) -> void* {
        void* r = (void*)p;
        p += (bytes + 255) & ~(size_t)255;
        return r;
    };
    float*  bufA   = (float*)alloc((size_t)N * HD * 4);   // XR / h (in-place chain)
    float*  bufXL  = (float*)alloc((size_t)N * HD * 4);   // XL (gather target)
    float*  bufH0  = (float*)alloc((size_t)N * CH * 4);   // encoder output
    int*    cnt    = (int*)alloc((size_t)N * 4);
    int*    off    = (int*)alloc((size_t)(N + 1) * 4);
    int*    eidx   = (int*)alloc((size_t)E * 4);
    const int nb   = (N + 255) / 256;
    int*    bsum   = (int*)alloc((size_t)nb * 4);
    int*    bpre   = (int*)alloc((size_t)nb * 4);
    float*  pooled = (float*)alloc(64 * HD * 4);
    float*  gcnt   = (float*)alloc(64 * 4);
    ushort* wfrag1 = (ushort*)alloc((size_t)64 * 64 * 16 * 2 * 2);   // K=64 hi+lo
    ushort* wfrag2 = (ushort*)alloc((size_t)256 * 64 * 16 * 2 * 2);  // K=256 hi+lo

    // ---- weight prep (B-frag, hi/lo regions) ----
    prep_w<<<16, 256, 0, stream>>>(g1_Wl, g1_Wr, wfrag1, 64);
    prep_w<<<64, 256, 0, stream>>>(g2_Wl, g2_Wr, wfrag2, 256);

    // ---- CSR by dst (built once, reused for both GAT layers) ----
    zero_int<<<nb, 256, 0, stream>>>(cnt, N);
    deg_kernel<<<(E + 255) / 256, 256, 0, stream>>>(dst, cnt, E);
    scan_block<<<nb, 256, 0, stream>>>(cnt, off, bsum, N);
    scan_bsum<<<1, 512, 0, stream>>>(bsum, bpre, nb);
    scan_add<<<nb, 256, 0, stream>>>(off, bpre, N);
    zero_int<<<nb, 256, 0, stream>>>(cnt, N);
    scatter_kernel<<<(E + 255) / 256, 256, 0, stream>>>(dst, off, cnt, eidx, E);

    // ---- encoder ----
    encoder_kernel<<<(N * 64 + 255) / 256, 256, 0, stream>>>(x, W_enc, b_enc, bufH0, N);

    const int gblocks = (N + 63) / 64;

    // ---- GAT layer 1: h0 -> XL(bufXL), XR(bufA); aggregate -> h1 in-place(bufA)
    gemm_mfma<64><<<gblocks, 512, 0, stream>>>(
        bufH0, wfrag1, g1_bl, g1_br, bufXL, bufA, N);
    gat_aggregate<<<(N + 3) / 4, 256, 0, stream>>>(
        bufXL, bufA, eattr, src, off, eidx, g1_We, g1_att, g1_bias, bufA, N);

    // ---- GAT layer 2: h1(bufA) -> XL(bufXL), XR in-place(bufA); aggregate -> h2(bufA)
    gemm_mfma<256><<<gblocks, 512, 0, stream>>>(
        bufA, wfrag2, g2_bl, g2_br, bufXL, bufA, N);
    gat_aggregate<<<(N + 3) / 4, 256, 0, stream>>>(
        bufXL, bufA, eattr, src, off, eidx, g2_We, g2_att, g2_bias, bufA, N);

    // ---- pool + MLP head ----
    zero_int<<<(64 * HD + 255) / 256, 256, 0, stream>>>((int*)pooled, 64 * HD);
    pool_kernel<<<64 * 8, 256, 0, stream>>>(bufA, batch, pooled, gcnt, N);
    mlp_kernel<<<64, 128, 0, stream>>>(pooled, gcnt, W_p1, b_p1, ln_g, ln_b,
                                       W_p2, b_p2, W_head, b_head, (float*)d_out);
}

// Round 6
// 613.921 us; speedup vs baseline: 1.7104x; 1.1618x over previous
//
#include <hip/hip_runtime.h>
#include <math.h>

// Problem constants: N=100000, E=400000, G=64, IN=8, H=4, C=64, HD=256.
// GEMMs: split-bf16 MFMA (hi+lo, 3-term) for fp32-class accuracy.
// R6: gat_aggregate remapped to lane = head*16 + quarter (float4/lane):
// 4-shfl simultaneous head reductions, 2 expf/edge, coalesced float4 gathers;
// src/eattr pre-gathered into CSR order (srcg/eag) to kill the eidx chain.

#define HD 256
#define NHEAD 4
#define CH 64

typedef __attribute__((ext_vector_type(8))) short bf16x8;
typedef __attribute__((ext_vector_type(4))) float f32x4;

__device__ __forceinline__ unsigned f2bf_hibits(float f) {
    unsigned u = __float_as_uint(f);
    return (u + 0x7fffu + ((u >> 16) & 1u)) & 0xffff0000u;   // RNE, as high bits
}

// ---------------------------------------------------------------------------
__global__ void zero_int(int* __restrict__ p, int n) {
    int i = blockIdx.x * 256 + threadIdx.x;
    if (i < n) p[i] = 0;
}

// ---------------------------------------------------------------------------
// CSR build: degree histogram -> 3-step exclusive scan -> scatter (gathers
// src and eattr into CSR order so the aggregate loop has no indirection).
// ---------------------------------------------------------------------------
__global__ void deg_kernel(const int* __restrict__ dst, int* __restrict__ cnt, int E) {
    int e = blockIdx.x * 256 + threadIdx.x;
    if (e < E) atomicAdd(&cnt[dst[e]], 1);
}

__global__ void scan_block(const int* __restrict__ cnt, int* __restrict__ off,
                           int* __restrict__ bsum, int N) {
    __shared__ int s[256];
    int i = blockIdx.x * 256 + threadIdx.x;
    int v = (i < N) ? cnt[i] : 0;
    s[threadIdx.x] = v;
    __syncthreads();
    for (int d = 1; d < 256; d <<= 1) {
        int t = 0;
        if (threadIdx.x >= d) t = s[threadIdx.x - d];
        __syncthreads();
        s[threadIdx.x] += t;
        __syncthreads();
    }
    if (i < N) off[i + 1] = s[threadIdx.x];
    if (threadIdx.x == 255) bsum[blockIdx.x] = s[255];
    if (blockIdx.x == 0 && threadIdx.x == 0) off[0] = 0;
}

__global__ void scan_bsum(const int* __restrict__ bsum, int* __restrict__ bpre, int nb) {
    __shared__ int s[512];
    int t = threadIdx.x;
    s[t] = (t < nb) ? bsum[t] : 0;
    __syncthreads();
    for (int d = 1; d < 512; d <<= 1) {
        int x = 0;
        if (t >= d) x = s[t - d];
        __syncthreads();
        s[t] += x;
        __syncthreads();
    }
    if (t < nb) bpre[t] = s[t] - bsum[t];
}

__global__ void scan_add(int* __restrict__ off, const int* __restrict__ bpre, int N) {
    int i = blockIdx.x * 256 + threadIdx.x;
    if (i < N) off[i + 1] += bpre[blockIdx.x];
}

__global__ void scatter_kernel(const int* __restrict__ dst, const int* __restrict__ src,
                               const float* __restrict__ eattr, const int* __restrict__ off,
                               int* __restrict__ cur, int* __restrict__ srcg,
                               float* __restrict__ eag, int E) {
    int e = blockIdx.x * 256 + threadIdx.x;
    if (e < E) {
        int d = dst[e];
        int p = atomicAdd(&cur[d], 1);
        int t = off[d] + p;
        srcg[t] = src[e];
        eag[t] = eattr[e];
    }
}

// ---------------------------------------------------------------------------
// Encoder: h0[N,64] = relu(x[N,8] @ W_enc[8,64] + b_enc)
// ---------------------------------------------------------------------------
__global__ void encoder_kernel(const float* __restrict__ x, const float* __restrict__ W,
                               const float* __restrict__ b, float* __restrict__ h, int N) {
    int idx = blockIdx.x * 256 + threadIdx.x;
    if (idx >= N * 64) return;
    int n = idx >> 6, c = idx & 63;
    float v = b[c];
#pragma unroll
    for (int k = 0; k < 8; ++k) v = fmaf(x[n * 8 + k], W[k * 64 + c], v);
    h[idx] = fmaxf(v, 0.f);
}

// ---------------------------------------------------------------------------
// prep_w: Wl,Wr [K,256] fp32 -> B-frag layout. hi region then lo region.
// ---------------------------------------------------------------------------
__global__ void prep_w(const float* __restrict__ Wl, const float* __restrict__ Wr,
                       ushort* __restrict__ frag, int K) {
    int t = blockIdx.x * 256 + threadIdx.x;
    int total = K * 64;
    if (t >= total) return;
    int l = t & 63;
    int ct = (t >> 6) & 31;
    int ks = t >> 11;
    int n = l & 15, q = l >> 4;
    const float* W = (ct < 16) ? Wl : Wr;
    int col = (ct & 15) * 16 + n;
    ushort* phi = frag + (size_t)t * 8;
    ushort* plo = frag + (size_t)total * 8 + (size_t)t * 8;
#pragma unroll
    for (int j = 0; j < 8; ++j) {
        int k = ks * 32 + q * 8 + j;
        float wv = W[(size_t)k * 256 + col];
        unsigned h = f2bf_hibits(wv);
        phi[j] = (ushort)(h >> 16);
        float lof = wv - __uint_as_float(h);
        plo[j] = (ushort)(f2bf_hibits(lof) >> 16);
    }
}

// ---------------------------------------------------------------------------
// Split-bf16 MFMA dual GEMM (R5 structure, unchanged).
// ---------------------------------------------------------------------------
template <int K>
__global__ __launch_bounds__(512, 4) void gemm_mfma(
    const float* A, const ushort* __restrict__ Bfrag,
    const float* __restrict__ bl, const float* __restrict__ br,
    float* __restrict__ outL, float* outR, int N) {
    constexpr int KS = K / 32;
    constexpr int C4 = K / 4;
    constexpr int LC4 = (K == 256) ? 6 : 4;
    constexpr int FRAG_SHORTS = KS * 4 * 64 * 8;
    constexpr size_t LO_OFF = (size_t)K * 64 * 8;
    __shared__ ushort fragHi[FRAG_SHORTS];
    __shared__ ushort fragLo[FRAG_SHORTS];

    const int t = threadIdx.x;
    const int row0 = blockIdx.x * 64;

#pragma unroll
    for (int it = 0; it < (64 * C4) / 512; ++it) {
        int jj = it * 512 + t;
        int m = jj & 15;
        int c4 = (jj >> 4) & (C4 - 1);
        int rg = jj >> (4 + LC4);
        int row = row0 + rg * 16 + m;
        float4 v = make_float4(0.f, 0.f, 0.f, 0.f);
        if (row < N) v = *(const float4*)(A + (size_t)row * K + c4 * 4);
        int c = c4 * 4;
        int ks = c >> 5, q = (c >> 3) & 3, j = c & 7;
        int cell = (ks * 4 + rg) * 64 + m + 16 * q;
        float f[4] = {v.x, v.y, v.z, v.w};
        ushort h4[4], l4[4];
#pragma unroll
        for (int u = 0; u < 4; ++u) {
            unsigned hb = f2bf_hibits(f[u]);
            h4[u] = (ushort)(hb >> 16);
            l4[u] = (ushort)(f2bf_hibits(f[u] - __uint_as_float(hb)) >> 16);
        }
        *(ushort4*)(fragHi + cell * 8 + j) = make_ushort4(h4[0], h4[1], h4[2], h4[3]);
        *(ushort4*)(fragLo + cell * 8 + j) = make_ushort4(l4[0], l4[1], l4[2], l4[3]);
    }
    __syncthreads();

    const int w = t >> 6, l = t & 63;
    const int ct0 = w * 4;

    f32x4 acc[4][4];
#pragma unroll
    for (int rt = 0; rt < 4; ++rt)
#pragma unroll
        for (int c = 0; c < 4; ++c) acc[rt][c] = (f32x4){0.f, 0.f, 0.f, 0.f};

    for (int ks = 0; ks < KS; ++ks) {
        bf16x8 ah[4], al[4];
#pragma unroll
        for (int rt = 0; rt < 4; ++rt) {
            int cell = (ks * 4 + rt) * 64 + l;
            ah[rt] = *(const bf16x8*)(fragHi + cell * 8);
            al[rt] = *(const bf16x8*)(fragLo + cell * 8);
        }
#pragma unroll
        for (int c = 0; c < 4; ++c) {
            size_t e = ((size_t)(ks * 32 + ct0 + c) * 64 + l) * 8;
            bf16x8 bh = *(const bf16x8*)(Bfrag + e);
            bf16x8 bo = *(const bf16x8*)(Bfrag + LO_OFF + e);
#pragma unroll
            for (int rt = 0; rt < 4; ++rt) {
                acc[rt][c] = __builtin_amdgcn_mfma_f32_16x16x32_bf16(ah[rt], bh, acc[rt][c], 0, 0, 0);
                acc[rt][c] = __builtin_amdgcn_mfma_f32_16x16x32_bf16(al[rt], bh, acc[rt][c], 0, 0, 0);
                acc[rt][c] = __builtin_amdgcn_mfma_f32_16x16x32_bf16(ah[rt], bo, acc[rt][c], 0, 0, 0);
            }
        }
    }

    const int m = l & 15, q = l >> 4;
    const float* bias = (w < 4) ? bl : br;
    float* outp = (w < 4) ? outL : outR;
#pragma unroll
    for (int c = 0; c < 4; ++c) {
        int colbase = ((ct0 + c) & 15) * 16 + m;
        float bb = bias[colbase];
#pragma unroll
        for (int rt = 0; rt < 4; ++rt) {
#pragma unroll
            for (int r = 0; r < 4; ++r) {
                int row = row0 + rt * 16 + q * 4 + r;
                if (row < N) outp[(size_t)row * 256 + colbase] = acc[rt][c][r] + bb;
            }
        }
    }
}

// ---------------------------------------------------------------------------
// GATv2 aggregation (R6): wave per node; lane = head*16 + quarter; each lane
// owns 4 consecutive channels (float4) of one head. Per edge: coalesced
// float4 gather of xl[src], 16-lane logit reduction (all 4 heads in parallel
// via quadrant-local xor shuffles), 2 __expf online-softmax update.
// out may ALIAS xr (node i's xr read only by node i's wave).
// ---------------------------------------------------------------------------
__global__ __launch_bounds__(256) void gat_aggregate(
    const float* __restrict__ xl, const float* xr,
    const int* __restrict__ off, const int* __restrict__ srcg,
    const float* __restrict__ eag,
    const float* __restrict__ We, const float* __restrict__ att,
    const float* __restrict__ bias, float* out, int N) {
    int node = blockIdx.x * 4 + (threadIdx.x >> 6);
    if (node >= N) return;
    int lane = threadIdx.x & 63;
    int cbase = (lane >> 4) * 64 + (lane & 15) * 4;   // head*64 + quarter*4

    float4 we4 = *(const float4*)(We + cbase);
    float4 at4 = *(const float4*)(att + cbase);
    size_t nb = (size_t)node * HD;
    float4 xr4 = *(const float4*)(xr + nb + cbase);
    float4 b4 = *(const float4*)(bias + cbase);

    float m = -1e30f, l = 0.f;
    float4 acc = make_float4(0.f, 0.f, 0.f, 0.f);

    int s0 = off[node], s1 = off[node + 1];
    for (int t = s0; t < s1; ++t) {
        int j = srcg[t];
        float ea = eag[t];
        float4 xl4 = *(const float4*)(xl + (size_t)j * HD + cbase);
        float v0 = fmaf(ea, we4.x, xl4.x + xr4.x);
        float v1 = fmaf(ea, we4.y, xl4.y + xr4.y);
        float v2 = fmaf(ea, we4.z, xl4.z + xr4.z);
        float v3 = fmaf(ea, we4.w, xl4.w + xr4.w);
        // leaky_relu(0.2): max(v,0) + 0.2*min(v,0)
        v0 = fmaf(0.2f, fminf(v0, 0.f), fmaxf(v0, 0.f));
        v1 = fmaf(0.2f, fminf(v1, 0.f), fmaxf(v1, 0.f));
        v2 = fmaf(0.2f, fminf(v2, 0.f), fmaxf(v2, 0.f));
        v3 = fmaf(0.2f, fminf(v3, 0.f), fmaxf(v3, 0.f));
        float r = at4.x * v0;
        r = fmaf(at4.y, v1, r);
        r = fmaf(at4.z, v2, r);
        r = fmaf(at4.w, v3, r);
        // reduce over the 16-lane quadrant: all 4 heads simultaneously
        r += __shfl_xor(r, 1);
        r += __shfl_xor(r, 2);
        r += __shfl_xor(r, 4);
        r += __shfl_xor(r, 8);
        // online softmax (per-lane = per-head state)
        float mn = fmaxf(m, r);
        float sc = __expf(m - mn);
        float p = __expf(r - mn);
        l = fmaf(l, sc, p);
        acc.x = fmaf(acc.x, sc, p * xl4.x);
        acc.y = fmaf(acc.y, sc, p * xl4.y);
        acc.z = fmaf(acc.z, sc, p * xl4.z);
        acc.w = fmaf(acc.w, sc, p * xl4.w);
        m = mn;
    }
    float inv = 1.f / (l + 1e-16f);
    float4 o;
    o.x = fmaxf(fmaf(acc.x, inv, b4.x), 0.f);
    o.y = fmaxf(fmaf(acc.y, inv, b4.y), 0.f);
    o.z = fmaxf(fmaf(acc.z, inv, b4.z), 0.f);
    o.w = fmaxf(fmaf(acc.w, inv, b4.w), 0.f);
    *(float4*)(out + nb + cbase) = o;
}

// ---------------------------------------------------------------------------
__device__ __forceinline__ int lowerb(const int* b, int n, int v) {
    int lo = 0, hi = n;
    while (lo < hi) {
        int mid = (lo + hi) >> 1;
        if (b[mid] < v) lo = mid + 1; else hi = mid;
    }
    return lo;
}

__global__ void pool_kernel(const float* __restrict__ h, const int* __restrict__ batch,
                            float* __restrict__ pooled, float* __restrict__ gcnt, int N) {
    int g = blockIdx.x >> 3, part = blockIdx.x & 7;
    int start = lowerb(batch, N, g);
    int end = lowerb(batch, N, g + 1);
    int rows = end - start;
    int r0 = start + (int)((long long)rows * part / 8);
    int r1 = start + (int)((long long)rows * (part + 1) / 8);
    int c = threadIdx.x;
    float s = 0.f;
    for (int r = r0; r < r1; ++r) s += h[(size_t)r * HD + c];
    atomicAdd(&pooled[g * HD + c], s);
    if (part == 0 && c == 0) gcnt[g] = (float)rows;
}

// ---------------------------------------------------------------------------
__global__ void mlp_kernel(const float* __restrict__ pooled, const float* __restrict__ gcnt,
                           const float* __restrict__ W_p1, const float* __restrict__ b_p1,
                           const float* __restrict__ ln_g, const float* __restrict__ ln_b,
                           const float* __restrict__ W_p2, const float* __restrict__ b_p2,
                           const float* __restrict__ W_head, const float* __restrict__ b_head,
                           float* __restrict__ out) {
    int g = blockIdx.x;
    int j = threadIdx.x;
    __shared__ float sh[128];
    __shared__ float red[2];

    float inv = 1.f / fmaxf(gcnt[g], 1.f);
    float v = b_p1[j];
    for (int k = 0; k < 256; ++k) v = fmaf(pooled[g * 256 + k] * inv, W_p1[k * 128 + j], v);

    float s = v;
    for (int o = 32; o > 0; o >>= 1) s += __shfl_xor(s, o);
    if ((j & 63) == 0) red[j >> 6] = s;
    __syncthreads();
    float mu = (red[0] + red[1]) * (1.f / 128.f);
    float d = v - mu;
    float s2 = d * d;
    for (int o = 32; o > 0; o >>= 1) s2 += __shfl_xor(s2, o);
    __syncthreads();
    if ((j & 63) == 0) red[j >> 6] = s2;
    __syncthreads();
    float var = (red[0] + red[1]) * (1.f / 128.f);

    float p = d * rsqrtf(var + 1e-5f) * ln_g[j] + ln_b[j];
    sh[j] = fmaxf(p, 0.f);
    __syncthreads();

    if (j < 64) {
        float q = b_p2[j];
        for (int k = 0; k < 128; ++k) q = fmaf(sh[k], W_p2[k * 64 + j], q);
        q = fmaxf(q, 0.f);
        float t = q * W_head[j];
        for (int o = 32; o > 0; o >>= 1) t += __shfl_xor(t, o);
        if (j == 0) out[g] = t + b_head[0];
    }
}

// ---------------------------------------------------------------------------
extern "C" void kernel_launch(void* const* d_in, const int* in_sizes, int n_in,
                              void* d_out, int out_size, void* d_ws, size_t ws_size,
                              hipStream_t stream) {
    const float* x      = (const float*)d_in[0];
    const float* eattr  = (const float*)d_in[1];
    const int*   src    = (const int*)d_in[2];
    const int*   dst    = (const int*)d_in[3];
    const int*   batch  = (const int*)d_in[4];
    const float* W_enc  = (const float*)d_in[5];
    const float* b_enc  = (const float*)d_in[6];
    const float* g1_Wl  = (const float*)d_in[7];
    const float* g1_bl  = (const float*)d_in[8];
    const float* g1_Wr  = (const float*)d_in[9];
    const float* g1_br  = (const float*)d_in[10];
    const float* g1_We  = (const float*)d_in[11];
    const float* g1_att = (const float*)d_in[12];
    const float* g1_bias= (const float*)d_in[13];
    const float* g2_Wl  = (const float*)d_in[14];
    const float* g2_bl  = (const float*)d_in[15];
    const float* g2_Wr  = (const float*)d_in[16];
    const float* g2_br  = (const float*)d_in[17];
    const float* g2_We  = (const float*)d_in[18];
    const float* g2_att = (const float*)d_in[19];
    const float* g2_bias= (const float*)d_in[20];
    const float* W_p1   = (const float*)d_in[21];
    const float* b_p1   = (const float*)d_in[22];
    const float* ln_g   = (const float*)d_in[23];
    const float* ln_b   = (const float*)d_in[24];
    const float* W_p2   = (const float*)d_in[25];
    const float* b_p2   = (const float*)d_in[26];
    const float* W_head = (const float*)d_in[27];
    const float* b_head = (const float*)d_in[28];

    const int N = in_sizes[0] / 8;   // 100000
    const int E = in_sizes[2];       // 400000

    // workspace layout (~236 MB)
    char* p = (char*)d_ws;
    auto alloc = [&](size_t bytes) -> void* {
        void* r = (void*)p;
        p += (bytes + 255) & ~(size_t)255;
        return r;
    };
    float*  bufA   = (float*)alloc((size_t)N * HD * 4);   // XR / h (in-place chain)
    float*  bufXL  = (float*)alloc((size_t)N * HD * 4);   // XL (gather target)
    float*  bufH0  = (float*)alloc((size_t)N * CH * 4);   // encoder output
    int*    cnt    = (int*)alloc((size_t)N * 4);
    int*    off    = (int*)alloc((size_t)(N + 1) * 4);
    int*    srcg   = (int*)alloc((size_t)E * 4);          // src in CSR order
    float*  eag    = (float*)alloc((size_t)E * 4);        // eattr in CSR order
    const int nb   = (N + 255) / 256;
    int*    bsum   = (int*)alloc((size_t)nb * 4);
    int*    bpre   = (int*)alloc((size_t)nb * 4);
    float*  pooled = (float*)alloc(64 * HD * 4);
    float*  gcnt   = (float*)alloc(64 * 4);
    ushort* wfrag1 = (ushort*)alloc((size_t)64 * 64 * 16 * 2 * 2);   // K=64 hi+lo
    ushort* wfrag2 = (ushort*)alloc((size_t)256 * 64 * 16 * 2 * 2);  // K=256 hi+lo

    // ---- weight prep (B-frag, hi/lo regions) ----
    prep_w<<<16, 256, 0, stream>>>(g1_Wl, g1_Wr, wfrag1, 64);
    prep_w<<<64, 256, 0, stream>>>(g2_Wl, g2_Wr, wfrag2, 256);

    // ---- CSR by dst (built once, reused for both GAT layers) ----
    zero_int<<<nb, 256, 0, stream>>>(cnt, N);
    deg_kernel<<<(E + 255) / 256, 256, 0, stream>>>(dst, cnt, E);
    scan_block<<<nb, 256, 0, stream>>>(cnt, off, bsum, N);
    scan_bsum<<<1, 512, 0, stream>>>(bsum, bpre, nb);
    scan_add<<<nb, 256, 0, stream>>>(off, bpre, N);
    zero_int<<<nb, 256, 0, stream>>>(cnt, N);
    scatter_kernel<<<(E + 255) / 256, 256, 0, stream>>>(dst, src, eattr, off, cnt,
                                                        srcg, eag, E);

    // ---- encoder ----
    encoder_kernel<<<(N * 64 + 255) / 256, 256, 0, stream>>>(x, W_enc, b_enc, bufH0, N);

    const int gblocks = (N + 63) / 64;

    // ---- GAT layer 1: h0 -> XL(bufXL), XR(bufA); aggregate -> h1 in-place(bufA)
    gemm_mfma<64><<<gblocks, 512, 0, stream>>>(
        bufH0, wfrag1, g1_bl, g1_br, bufXL, bufA, N);
    gat_aggregate<<<(N + 3) / 4, 256, 0, stream>>>(
        bufXL, bufA, off, srcg, eag, g1_We, g1_att, g1_bias, bufA, N);

    // ---- GAT layer 2: h1(bufA) -> XL(bufXL), XR in-place(bufA); aggregate -> h2(bufA)
    gemm_mfma<256><<<gblocks, 512, 0, stream>>>(
        bufA, wfrag2, g2_bl, g2_br, bufXL, bufA, N);
    gat_aggregate<<<(N + 3) / 4, 256, 0, stream>>>(
        bufXL, bufA, off, srcg, eag, g2_We, g2_att, g2_bias, bufA, N);

    // ---- pool + MLP head ----
    zero_int<<<(64 * HD + 255) / 256, 256, 0, stream>>>((int*)pooled, 64 * HD);
    pool_kernel<<<64 * 8, 256, 0, stream>>>(bufA, batch, pooled, gcnt, N);
    mlp_kernel<<<64, 128, 0, stream>>>(pooled, gcnt, W_p1, b_p1, ln_g, ln_b,
                                       W_p2, b_p2, W_head, b_head, (float*)d_out);
}